// Round 13
// baseline (894.635 us; speedup 1.0000x reference)
//
#include <hip/hip_runtime.h>
#include <math.h>

typedef __bf16 bf16;
typedef __bf16 bf16x8 __attribute__((ext_vector_type(8)));
typedef __bf16 bf16x4 __attribute__((ext_vector_type(4)));
typedef __bf16 bf16x2 __attribute__((ext_vector_type(2)));
typedef float f32x4 __attribute__((ext_vector_type(4)));

#define N_NODES 10000
#define N_EDGES 80000
#define N_GRAPHS 64

template<int EPL> struct VecT;
template<> struct VecT<8>{ typedef bf16x8 type; };
template<> struct VecT<4>{ typedef bf16x4 type; };
template<> struct VecT<2>{ typedef bf16x2 type; };

__device__ inline unsigned f2ord(float f){
  unsigned u = __float_as_uint(f);
  return (u & 0x80000000u) ? ~u : (u | 0x80000000u);
}
__device__ inline float ord2f(unsigned u){
  return (u & 0x80000000u) ? __uint_as_float(u & 0x7fffffffu) : __uint_as_float(~u);
}

__device__ inline void gload_lds16(const bf16* g, bf16* l){
  __builtin_amdgcn_global_load_lds(
      (const __attribute__((address_space(1))) unsigned int*)g,
      (__attribute__((address_space(3))) unsigned int*)l, 16, 0, 0);
}

__global__ __launch_bounds__(256) void detect_f32_k(const unsigned short* __restrict__ raw, int n,
                                                    int* __restrict__ flagF){
  int i = blockIdx.x*256 + threadIdx.x;
  if (i < n){
    unsigned e = (raw[i] >> 7) & 0xFFu;
    if (e >= 0xC0u) atomicOr(flagF, 1);
  }
}

// ---- batched conversion with strided-dst support ----
struct CvPack {
  const void* src[11];
  bf16* dst[11];
  int pre[12];
  int rl[11];
  int st[11];
};
__global__ __launch_bounds__(256) void convert_all(CvPack p, const int* __restrict__ flagF){
  int gid = blockIdx.x*256 + threadIdx.x;
  if (gid >= p.pre[11]) return;
  int t = 0;
  while (gid >= p.pre[t+1]) ++t;
  int i = gid - p.pre[t];
  bool f = (*flagF != 0);
  float v = f ? ((const float*)p.src[t])[i] : (float)((const bf16*)p.src[t])[i];
  int row = i / p.rl[t], col = i - row*p.rl[t];
  p.dst[t][(size_t)row*p.st[t] + col] = (bf16)v;
}

__global__ __launch_bounds__(256) void detect_i64(const int* __restrict__ raw, int* __restrict__ flag){
  int i = blockIdx.x*256 + threadIdx.x;
  if (i < 4000 && raw[2*i+1] != 0) atomicOr(flag, 1);   // flag!=0 => int32
}

// conv_idx + degree count fused (cnt pre-zeroed via memset)
__global__ __launch_bounds__(256) void conv_idx(const int* __restrict__ ei_raw,
                                                const int* __restrict__ b_raw,
                                                const int* __restrict__ flag,
                                                int* __restrict__ src, int* __restrict__ dst,
                                                int* __restrict__ bat, int* __restrict__ cnt){
  int i = blockIdx.x*256 + threadIdx.x;
  bool i32 = (*flag != 0);
  if (i < N_EDGES){
    int s = i32 ? ei_raw[i]   : ei_raw[2*i];
    int d = i32 ? ei_raw[N_EDGES + i] : ei_raw[2*(N_EDGES + i)];
    s = min(max(s, 0), N_NODES-1);
    d = min(max(d, 0), N_NODES-1);
    src[i] = s; dst[i] = d;
    atomicAdd(&cnt[d], 1);
  }
  if (i < N_NODES){
    int b = i32 ? b_raw[i] : b_raw[2*i];
    bat[i] = min(max(b, 0), N_GRAPHS-1);
  }
}

// ---------------- parallel scan (3 small dispatches) ----------------
__global__ __launch_bounds__(256) void scanA(const int* __restrict__ cnt, int* __restrict__ fill,
                                             int* __restrict__ bsum, int N){
  __shared__ int s[256];
  int i = blockIdx.x*256 + threadIdx.x;
  int v = (i < N) ? cnt[i] : 0;
  s[threadIdx.x] = v;
  __syncthreads();
  for (int d = 1; d < 256; d <<= 1){
    int t = (threadIdx.x >= d) ? s[threadIdx.x - d] : 0;
    __syncthreads();
    s[threadIdx.x] += t;
    __syncthreads();
  }
  if (i < N) fill[i] = s[threadIdx.x] - v;          // block-exclusive
  if (threadIdx.x == 255) bsum[blockIdx.x] = s[255];
}
__global__ __launch_bounds__(64) void scanB(int* __restrict__ bsum, int nb){
  if (threadIdx.x == 0){
    int a = 0;
    for (int b = 0; b < nb; ++b){ int t = bsum[b]; bsum[b] = a; a += t; }
  }
}
__global__ __launch_bounds__(256) void scanC(const int* __restrict__ bsum, int* __restrict__ fill,
                                             int* __restrict__ row_ptr, int N){
  int i = blockIdx.x*256 + threadIdx.x;
  if (i < N){
    int st = fill[i] + bsum[i >> 8];
    fill[i] = st;
    row_ptr[i] = st;
  }
  if (i == 0) row_ptr[N] = N_EDGES;   // dst clamped -> every edge counted
}

__global__ __launch_bounds__(256) void fill_csr(const int* __restrict__ dst,
                                                int* __restrict__ fill, int* __restrict__ eids){
  int e = blockIdx.x*256 + threadIdx.x;
  if (e < N_EDGES){
    int p = atomicAdd(&fill[dst[e]], 1);
    eids[p] = e;
  }
}

// ---------------- GEMM: C[M][N] = A[M][K](lda) @ Bt[N][K] + bias ----------------
__global__ __launch_bounds__(256)
void gemm_bias(const bf16* __restrict__ A, int lda,
               const bf16* __restrict__ Bt,
               const bf16* __restrict__ bias, bf16* __restrict__ Cout, int ldc,
               int M, int N, int K)
{
  __shared__ bf16 As[128*64];
  __shared__ bf16 Bs[128*64];
  const int tid = threadIdx.x;
  const int lane = tid & 63;
  const int wave = tid >> 6;
  const int m0 = blockIdx.y * 128, n0 = blockIdx.x * 128;
  const int wm = (wave >> 1) * 64, wn = (wave & 1) * 64;
  const int l15 = lane & 15, l4 = lane >> 4;
  const int srow = lane >> 3;
  const int schunk = lane & 7;

  f32x4 acc[4][4] = {};

  for (int k0 = 0; k0 < K; k0 += 64){
    #pragma unroll
    for (int j = 0; j < 4; ++j){
      int r0 = (wave*4 + j)*8;
      int r  = r0 + srow;
      int gc = schunk ^ (r & 7);
      int ga = m0 + r; if (ga >= M) ga = M-1;
      gload_lds16(A  + (size_t)ga*lda      + k0 + gc*8, As + r0*64);
      gload_lds16(Bt + (size_t)(n0 + r)*K  + k0 + gc*8, Bs + r0*64);
    }
    __syncthreads();
    #pragma unroll
    for (int kt = 0; kt < 2; ++kt){
      bf16x8 af[4], bfr[4];
      #pragma unroll
      for (int mt = 0; mt < 4; ++mt){
        int row = wm + mt*16 + l15;
        int p = (kt*4 + l4) ^ (l15 & 7);
        af[mt] = *(const bf16x8*)(As + row*64 + p*8);
      }
      #pragma unroll
      for (int nt = 0; nt < 4; ++nt){
        int row = wn + nt*16 + l15;
        int p = (kt*4 + l4) ^ (l15 & 7);
        bfr[nt] = *(const bf16x8*)(Bs + row*64 + p*8);
      }
      #pragma unroll
      for (int mt = 0; mt < 4; ++mt)
        #pragma unroll
        for (int nt = 0; nt < 4; ++nt)
          acc[mt][nt] = __builtin_amdgcn_mfma_f32_16x16x32_bf16(af[mt], bfr[nt], acc[mt][nt], 0, 0, 0);
    }
    __syncthreads();
  }

  #pragma unroll
  for (int nt = 0; nt < 4; ++nt){
    int col = n0 + wn + nt*16 + l15;
    float bv = (float)bias[col];
    #pragma unroll
    for (int mt = 0; mt < 4; ++mt){
      int rbase = m0 + wm + mt*16 + l4*4;
      #pragma unroll
      for (int r = 0; r < 4; ++r){
        int row = rbase + r;
        if (row < M) Cout[(size_t)row*ldc + col] = (bf16)(acc[mt][nt][r] + bv);
      }
    }
  }
}

// ---------------- split-K GEMM, 128xNT tile: atomic f32 accumulate, no bias ----------------
// Wide-N tiles minimize A re-reads (grid_x = N/NT); parallelism from K-splits
// (extra splits cost only ~10 MB fp32 atomic writes each — cheap vs 92 MB A re-reads).
template<int NT>
__global__ __launch_bounds__(256)
void gemm_splitk(const bf16* __restrict__ A, int lda,
                 const bf16* __restrict__ Bt, float* __restrict__ Cacc,
                 int M, int N, int K, int ks)
{
  constexpr int NB = NT/32;            // per-wave n-subtiles (4 or 8)
  __shared__ bf16 As[128*64];
  __shared__ bf16 Bs[NT*64];
  const int tid = threadIdx.x;
  const int lane = tid & 63;
  const int wave = tid >> 6;
  const int m0 = blockIdx.y * 128, n0 = blockIdx.x * NT;
  const int wm = (wave >> 1) * 64, wn = (wave & 1) * (NT/2);
  const int l15 = lane & 15, l4 = lane >> 4;
  const int srow = lane >> 3;
  const int schunk = lane & 7;
  const int kb = blockIdx.z * ks;
  const int ke = min(K, kb + ks);

  f32x4 acc[4][NB] = {};

  for (int k0 = kb; k0 < ke; k0 += 64){
    #pragma unroll
    for (int j = 0; j < 4; ++j){
      int r0 = (wave*4 + j)*8;
      int r  = r0 + srow;
      int gc = schunk ^ (r & 7);
      int ga = m0 + r; if (ga >= M) ga = M-1;
      gload_lds16(A + (size_t)ga*lda + k0 + gc*8, As + r0*64);
    }
    #pragma unroll
    for (int j = 0; j < NB; ++j){
      int r0 = (wave*NB + j)*8;
      int r  = r0 + srow;
      int gc = schunk ^ (r & 7);
      gload_lds16(Bt + (size_t)(n0 + r)*K + k0 + gc*8, Bs + r0*64);
    }
    __syncthreads();
    #pragma unroll
    for (int kt = 0; kt < 2; ++kt){
      bf16x8 af[4], bfr[NB];
      #pragma unroll
      for (int mt = 0; mt < 4; ++mt){
        int row = wm + mt*16 + l15;
        int p = (kt*4 + l4) ^ (l15 & 7);
        af[mt] = *(const bf16x8*)(As + row*64 + p*8);
      }
      #pragma unroll
      for (int nt = 0; nt < NB; ++nt){
        int row = wn + nt*16 + l15;
        int p = (kt*4 + l4) ^ (l15 & 7);
        bfr[nt] = *(const bf16x8*)(Bs + row*64 + p*8);
      }
      #pragma unroll
      for (int mt = 0; mt < 4; ++mt)
        #pragma unroll
        for (int nt = 0; nt < NB; ++nt)
          acc[mt][nt] = __builtin_amdgcn_mfma_f32_16x16x32_bf16(af[mt], bfr[nt], acc[mt][nt], 0, 0, 0);
    }
    __syncthreads();
  }

  #pragma unroll
  for (int nt = 0; nt < NB; ++nt){
    int col = n0 + wn + nt*16 + l15;
    #pragma unroll
    for (int mt = 0; mt < 4; ++mt){
      int rbase = m0 + wm + mt*16 + l4*4;
      #pragma unroll
      for (int r = 0; r < 4; ++r){
        int row = rbase + r;
        if (row < M) atomicAdd(&Cacc[(size_t)row*N + col], acc[mt][nt][r]);
      }
    }
  }
}

// ---------------- finalize: bias + deg0 fixup + ELU + strided store ----------------
__global__ __launch_bounds__(256)
void finalize_out(const float* __restrict__ facc, const bf16* __restrict__ bp,
                  const bf16* __restrict__ mb, const int* __restrict__ row_ptr,
                  int shift, int mask, int total, bf16* __restrict__ out, int ldo)
{
  int idx = blockIdx.x*256 + threadIdx.x;
  if (idx >= total) return;
  int n = idx >> shift, c = idx & mask;
  bool d0 = (row_ptr[n+1] == row_ptr[n]);
  float v = facc[idx] + (float)bp[c] - (d0 ? (float)mb[c] : 0.f);
  v = (v > 0.f) ? v : (__expf(v) - 1.f);
  out[(size_t)n*ldo + c] = (bf16)v;
}

// ---------------- merged M_h precompute (all 3 layers, 1 dispatch) ----------------
struct MhPack { const bf16* wk[3]; const bf16* wq[3]; bf16* wzt[3]; int fin[3]; int c[3]; };
__global__ __launch_bounds__(256)
void gemm_mh_all(MhPack P)
{
  const int L = blockIdx.z >> 3, h = blockIdx.z & 7;
  const int Fin = P.fin[L], C = P.c[L];
  const int nb = Fin >> 7;
  if ((int)blockIdx.x >= nb || (int)blockIdx.y >= nb) return;
  __shared__ bf16 As[128*64];
  __shared__ bf16 Bs[128*64];
  const int ld = 8*C;
  const bf16* Ab = P.wk[L] + h*C;
  const bf16* Bb = P.wq[L] + h*C;
  bf16* Cb = P.wzt[L] + (size_t)h*Fin*Fin;
  const int tid = threadIdx.x;
  const int lane = tid & 63;
  const int wave = tid >> 6;
  const int m0 = blockIdx.y * 128, n0 = blockIdx.x * 128;
  const int wm = (wave >> 1) * 64, wn = (wave & 1) * 64;
  const int l15 = lane & 15, l4 = lane >> 4;
  const int srow = lane >> 3;
  const int schunk = lane & 7;

  f32x4 acc[4][4] = {};

  for (int k0 = 0; k0 < C; k0 += 64){
    #pragma unroll
    for (int j = 0; j < 4; ++j){
      int r0 = (wave*4 + j)*8;
      int r  = r0 + srow;
      int gc = schunk ^ (r & 7);
      gload_lds16(Ab + (size_t)(m0 + r)*ld + k0 + gc*8, As + r0*64);
      gload_lds16(Bb + (size_t)(n0 + r)*ld + k0 + gc*8, Bs + r0*64);
    }
    __syncthreads();
    #pragma unroll
    for (int kt = 0; kt < 2; ++kt){
      bf16x8 af[4], bfr[4];
      #pragma unroll
      for (int mt = 0; mt < 4; ++mt){
        int row = wm + mt*16 + l15;
        int p = (kt*4 + l4) ^ (l15 & 7);
        af[mt] = *(const bf16x8*)(As + row*64 + p*8);
      }
      #pragma unroll
      for (int nt = 0; nt < 4; ++nt){
        int row = wn + nt*16 + l15;
        int p = (kt*4 + l4) ^ (l15 & 7);
        bfr[nt] = *(const bf16x8*)(Bs + row*64 + p*8);
      }
      #pragma unroll
      for (int mt = 0; mt < 4; ++mt)
        #pragma unroll
        for (int nt = 0; nt < 4; ++nt)
          acc[mt][nt] = __builtin_amdgcn_mfma_f32_16x16x32_bf16(af[mt], bfr[nt], acc[mt][nt], 0, 0, 0);
    }
    __syncthreads();
  }

  #pragma unroll
  for (int nt = 0; nt < 4; ++nt){
    int col = n0 + wn + nt*16 + l15;
    #pragma unroll
    for (int mt = 0; mt < 4; ++mt){
      int rbase = m0 + wm + mt*16 + l4*4;
      #pragma unroll
      for (int r = 0; r < 4; ++r)
        Cb[(size_t)(rbase + r)*Fin + col] = (bf16)acc[mt][nt][r];
    }
  }
}

// ---------------- merged Wv/Ws prep (all 3 layers) ----------------
struct WvPack { const void* wv[3]; const void* ws[3]; bf16* bt[3]; int fin[3]; int c[3]; int bx[3]; int by[3]; };
__global__ __launch_bounds__(256)
void prep_wv_all(WvPack P, const int* __restrict__ flagF)
{
  const int L = blockIdx.z;
  if ((int)blockIdx.x >= P.bx[L] || (int)blockIdx.y >= P.by[L]) return;
  __shared__ float t[32][33];
  bool f = (*flagF != 0);
  const int Fin = P.fin[L], C = P.c[L];
  int k0 = blockIdx.x*32, j0 = blockIdx.y*32;
  int x = threadIdx.x & 31, y = threadIdx.x >> 5;
  const void* srcp; int nstride, cb; float sc; int i0;
  if (k0 < 8*Fin){
    int h = k0 / Fin; i0 = k0 - h*Fin;
    srcp = P.wv[L]; nstride = 8*C; cb = h*C + j0; sc = 0.125f;
  } else {
    i0 = k0 - 8*Fin;
    srcp = P.ws[L]; nstride = C; cb = j0; sc = 1.0f;
  }
  #pragma unroll
  for (int ii = 0; ii < 4; ++ii){
    int i = i0 + y + ii*8;
    size_t idx = (size_t)i*nstride + cb + x;
    float v = f ? ((const float*)srcp)[idx] : (float)((const bf16*)srcp)[idx];
    t[y + ii*8][x] = v*sc;
  }
  __syncthreads();
  #pragma unroll
  for (int ii = 0; ii < 4; ++ii){
    int j = j0 + y + ii*8;
    P.bt[L][(size_t)j*(9*Fin) + k0 + x] = (bf16)t[x][y + ii*8];
  }
}

// ---------------- merged small prep (all 3 layers), wave-per-row ----------------
struct SmPack { const bf16* wkc[3]; const void* bq[3]; const void* bv[3]; const void* bs[3];
                int fin[3]; int c[3]; bf16* tz[3]; bf16* bp[3]; bf16* mb[3]; int rb[3]; int bpb[3]; };
__global__ __launch_bounds__(256)
void prep_small_all(SmPack P, const int* __restrict__ flagF)
{
  const int L = blockIdx.z;
  const int Fin = P.fin[L], C = P.c[L];
  const int rb = P.rb[L];
  if ((int)blockIdx.x >= rb + P.bpb[L]) return;
  bool f = (*flagF != 0);
  if ((int)blockIdx.x < rb){
    int wave = threadIdx.x >> 6, lane = threadIdx.x & 63;
    int r = blockIdx.x*4 + wave;            // r < 8*Fin (rb = 8*Fin/4)
    int h = r / Fin, i = r - h*Fin;
    int epc = C >> 6;
    const bf16* wp = P.wkc[L] + (size_t)i*8*C + h*C;
    const void* bqp = P.bq[L];
    float s = 0.f;
    for (int k = 0; k < epc; ++k){
      int c = k*64 + lane;
      float b = f ? ((const float*)bqp)[h*C + c] : (float)((const bf16*)bqp)[h*C + c];
      s += (float)wp[c] * b;
    }
    #pragma unroll
    for (int o = 32; o; o >>= 1) s += __shfl_xor(s, o, 64);
    if (lane == 0) P.tz[L][r] = (bf16)s;
  } else {
    int idx = ((int)blockIdx.x - rb)*256 + threadIdx.x;
    if (idx < C){
      float s = 0.f;
      for (int h = 0; h < 8; ++h)
        s += f ? ((const float*)P.bv[L])[h*C + idx] : (float)((const bf16*)P.bv[L])[h*C + idx];
      s *= 0.125f;
      float bsv = f ? ((const float*)P.bs[L])[idx] : (float)((const bf16*)P.bs[L])[idx];
      P.mb[L][idx] = (bf16)s;
      P.bp[L][idx] = (bf16)(s + bsv);
    }
  }
}

// ---------------- edge phase: scores via z.h_s (bias pre-folded), softmax, P = sum alpha h_s ----
template<int Fin, int NH>
__global__ __launch_bounds__(256)
void node_edge(const bf16* __restrict__ z, int zw, int hbase,
               bf16* __restrict__ AP, int ldP,
               const int* __restrict__ row_ptr, const int* __restrict__ eids,
               const int* __restrict__ srcv, float scale)
{
  constexpr int EPL = Fin/64;
  constexpr int NQ  = Fin/128;
  typedef typename VecT<EPL>::type vecb;
  __shared__ int   sSrc[256];
  __shared__ float sw[4][NH][256];

  int n = blockIdx.x;
  int beg = row_ptr[n], deg = row_ptr[n+1] - beg;
  if (deg > 256) deg = 256;   // deg ~ Poisson(8); P(deg>256) ~ 0
  int wave = threadIdx.x >> 6, lane = threadIdx.x & 63;
  int sub = lane >> 4, sl = lane & 15;

  for (int i = threadIdx.x; i < deg; i += 256) sSrc[i] = srcv[eids[beg + i]];
  __syncthreads();

  float zr[NH][NQ*8];
  #pragma unroll
  for (int j = 0; j < NH; ++j){
    const bf16* zp = z + (size_t)n*zw + (wave + j*4)*Fin;
    #pragma unroll
    for (int c = 0; c < NQ; ++c){
      bf16x8 v = *(const bf16x8*)(zp + c*128 + sl*8);
      #pragma unroll
      for (int k = 0; k < 8; ++k) zr[j][c*8+k] = (float)v[k];
    }
  }

  float acc[NH][EPL];
  #pragma unroll
  for (int j = 0; j < NH; ++j)
    #pragma unroll
    for (int k = 0; k < EPL; ++k) acc[j][k] = 0.f;

  if (deg > 0){
    for (int i0 = 0; i0 < deg; i0 += 4){
      int e = i0 + sub;
      int sn = (e < deg) ? sSrc[e] : 0;
      float s[NH];
      #pragma unroll
      for (int j = 0; j < NH; ++j) s[j] = 0.f;
      const bf16* hp = AP + (size_t)sn*ldP + 8*Fin;
      #pragma unroll
      for (int c = 0; c < NQ; ++c){
        bf16x8 hv = *(const bf16x8*)(hp + c*128 + sl*8);
        #pragma unroll
        for (int k = 0; k < 8; ++k){
          float xv = (float)hv[k];
          #pragma unroll
          for (int j = 0; j < NH; ++j) s[j] += zr[j][c*8+k]*xv;
        }
      }
      #pragma unroll
      for (int j = 0; j < NH; ++j){
        #pragma unroll
        for (int o = 1; o < 16; o <<= 1) s[j] += __shfl_xor(s[j], o, 64);
      }
      if (sl == 0 && e < deg){
        #pragma unroll
        for (int j = 0; j < NH; ++j)
          sw[wave][j][e] = s[j] * scale;
      }
    }
    #pragma unroll
    for (int j = 0; j < NH; ++j){
      float m = -3.4e38f;
      for (int i = lane; i < deg; i += 64) m = fmaxf(m, sw[wave][j][i]);
      #pragma unroll
      for (int o = 32; o; o >>= 1) m = fmaxf(m, __shfl_xor(m, o, 64));
      float ss = 0.f;
      for (int i = lane; i < deg; i += 64) ss += __expf(sw[wave][j][i] - m);
      #pragma unroll
      for (int o = 32; o; o >>= 1) ss += __shfl_xor(ss, o, 64);
      float inv = 1.f/(ss + 1e-16f);
      for (int i = lane; i < deg; i += 64) sw[wave][j][i] = __expf(sw[wave][j][i] - m)*inv;
    }
    for (int i = 0; i < deg; ++i){
      vecb hv = *(const vecb*)(AP + (size_t)sSrc[i]*ldP + 8*Fin + lane*EPL);
      #pragma unroll
      for (int j = 0; j < NH; ++j){
        float w = sw[wave][j][i];
        #pragma unroll
        for (int k = 0; k < EPL; ++k) acc[j][k] += w*(float)hv[k];
      }
    }
  }

  #pragma unroll
  for (int j = 0; j < NH; ++j){
    vecb outv;
    #pragma unroll
    for (int k = 0; k < EPL; ++k) outv[k] = (bf16)acc[j][k];
    *(vecb*)(AP + (size_t)n*ldP + (hbase + wave + j*4)*Fin + lane*EPL) = outv;
  }
}

// ---------------- pooling ----------------
__global__ __launch_bounds__(256) void gate_compute(const bf16* __restrict__ h, const bf16* __restrict__ wg,
                                                    const bf16* __restrict__ bg, const int* __restrict__ bat,
                                                    float* __restrict__ gate, unsigned* __restrict__ gmax){
  int n = blockIdx.x*4 + (threadIdx.x >> 6);
  if (n >= N_NODES) return;
  int lane = threadIdx.x & 63;
  const bf16* hr = h + (size_t)n*128;
  float s = (float)hr[lane]*(float)wg[lane] + (float)hr[64+lane]*(float)wg[64+lane];
  #pragma unroll
  for (int o = 32; o; o >>= 1) s += __shfl_xor(s, o, 64);
  if (lane == 0){
    float g = s + (float)bg[0];
    gate[n] = g;
    atomicMax(&gmax[bat[n]], f2ord(g));
  }
}

__global__ __launch_bounds__(256) void gate_expsum(float* __restrict__ gate, const int* __restrict__ bat,
                                                   const unsigned* __restrict__ gmax, float* __restrict__ gsum){
  int n = blockIdx.x*256 + threadIdx.x;
  if (n < N_NODES){
    float e = __expf(gate[n] - ord2f(gmax[bat[n]]));
    gate[n] = e;
    atomicAdd(&gsum[bat[n]], e);
  }
}

__global__ __launch_bounds__(256) void pool_weighted(const float* __restrict__ gate, const float* __restrict__ gsum,
                                                     const int* __restrict__ bat, const bf16* __restrict__ h,
                                                     float* __restrict__ gacc){
  int n = blockIdx.x*4 + (threadIdx.x >> 6);
  if (n >= N_NODES) return;
  int lane = threadIdx.x & 63;
  int b = bat[n];
  float w = gate[n]/(gsum[b] + 1e-16f);
  atomicAdd(&gacc[b*128 + lane],      w*(float)h[(size_t)n*128 + lane]);
  atomicAdd(&gacc[b*128 + 64 + lane], w*(float)h[(size_t)n*128 + 64 + lane]);
}

__global__ __launch_bounds__(64) void final_fc(const float* __restrict__ gacc, const bf16* __restrict__ wfc,
                                               const bf16* __restrict__ bfc, void* __restrict__ out,
                                               const int* __restrict__ flagF){
  int g = blockIdx.x;
  int o = threadIdx.x;
  if (o < 10){
    float s = (float)bfc[o];
    for (int c = 0; c < 128; ++c) s += gacc[g*128 + c]*(float)wfc[c*10 + o];
    if (*flagF) ((float*)out)[(size_t)g*10 + o] = s;
    else        ((bf16*)out)[(size_t)g*10 + o]  = (bf16)s;
  }
}

extern "C" void kernel_launch(void* const* d_in, const int* in_sizes, int n_in,
                              void* d_out, int out_size, void* d_ws, size_t ws_size,
                              hipStream_t stream)
{
  const int* ei   = (const int*)d_in[1];
  const int* braw = (const int*)d_in[2];

  // ---- workspace plan (arena-aliased); adaptive A2 size for one-shot layer-2 ----
  bf16 *Wzt1=0,*Wzt2=0,*Wzt3=0,*Wvt1=0,*Wvt2=0,*Wvt3=0;
  float *facc=0,*gate=0;
  bf16 *tz1=0,*tz2=0,*tz3=0,*bp1=0,*mb1=0,*bp2=0,*mb2=0,*bp3=0,*mb3=0,*h3=0;
  bf16 *cwg=0,*cbg=0,*cwfc=0,*cbfc=0;
  int *src=0,*dst=0,*bat=0,*cnt=0,*row_ptr=0,*fillp=0,*eids=0,*flagbuf=0;
  char *A1=0, *A2=0;

  auto plan = [&](bool big)->size_t{
    size_t off = 0;
    auto A = [&](size_t bytes)->char*{
      char* p = (char*)d_ws + off;
      off += (bytes + 255) & ~(size_t)255;
      return p;
    };
    A1 = A(92160000);
    A2 = A(big ? 81920000 : 46080000);
    Wzt1 = (bf16*)A((size_t)8*128*128*2);
    Wzt2 = (bf16*)A((size_t)8*512*512*2);
    Wzt3 = (bf16*)A((size_t)8*256*256*2);
    Wvt1 = (bf16*)A((size_t)512*9*128*2);
    Wvt2 = (bf16*)A((size_t)256*9*512*2);
    Wvt3 = (bf16*)A((size_t)128*9*256*2);
    facc = (float*)A((size_t)N_NODES*512*4);
    tz1  = (bf16*)A(8*128*2);
    tz2  = (bf16*)A(8*512*2);
    tz3  = (bf16*)A(8*256*2);
    bp1  = (bf16*)A(512*2);  mb1 = (bf16*)A(512*2);
    bp2  = (bf16*)A(256*2);  mb2 = (bf16*)A(256*2);
    bp3  = (bf16*)A(128*2);  mb3 = (bf16*)A(128*2);
    h3   = (bf16*)A((size_t)N_NODES*128*2);
    src  = (int*)A((size_t)N_EDGES*4);
    dst  = (int*)A((size_t)N_EDGES*4);
    bat  = (int*)A((size_t)N_NODES*4);
    cnt  = (int*)A((size_t)N_NODES*4);
    row_ptr = (int*)A((size_t)(N_NODES+1)*4);
    fillp= (int*)A((size_t)N_NODES*4);
    eids = (int*)A((size_t)N_EDGES*4);
    flagbuf = (int*)A(16384);
    gate = (float*)A((size_t)N_NODES*4);
    unsigned* poolz = (unsigned*)A((size_t)(64 + 64 + 64*128)*4);
    (void)poolz;
    cwg  = (bf16*)A(128*2);
    cbg  = (bf16*)A(2*2);
    cwfc = (bf16*)A(1280*2);
    cbfc = (bf16*)A(10*2);
    return off;
  };

  bool big = (plan(true) <= ws_size);
  if (!big && plan(false) > ws_size) return;   // floor plan doesn't fit; visible failure
  plan(big);
  unsigned* poolz = (unsigned*)((char*)gate + (((size_t)N_NODES*4 + 255) & ~(size_t)255));

  int* flagI = flagbuf;
  int* flagF = flagbuf + 1;
  int* bsum  = (int*)((char*)flagbuf + 8192);
  unsigned* gmax = poolz;
  float*    gsum = (float*)(poolz + 64);
  float*    gacc = (float*)(poolz + 128);

  bf16* AP1 = (bf16*)A2;   const int ldP1 = 1152;   // [P(1024)|x(128)]
  bf16* z1  = (bf16*)A1;
  bf16* AP2 = (bf16*)A1;   const int ldP2 = 4608;   // [P(4096)|h1(512)]
  bf16* z2  = (bf16*)A2;                            // group (2048w) or big (4096w)
  bf16* AP3 = (bf16*)A2;   const int ldP3 = 2304;   // [P(2048)|h2(256)]
  bf16* z3  = (bf16*)A1;
  bf16* wq1c = (bf16*)(A1 + 48000000);  bf16* wk1c = wq1c + 128*4096;
  bf16* wq2c = wk1c + 128*4096;         bf16* wk2c = wq2c + 512*2048;
  bf16* wq3c = wk2c + 512*2048;         bf16* wk3c = wq3c + 256*1024;

  // ---- detection ----
  hipMemsetAsync(flagbuf, 0, 16384, stream);
  {
    int nprobe = in_sizes[0] < 32768 ? in_sizes[0] : 32768;
    detect_f32_k<<<(nprobe + 255)/256, 256, 0, stream>>>((const unsigned short*)d_in[0], nprobe, flagF);
    detect_i64<<<16, 256, 0, stream>>>(ei, flagI);
  }

  // ---- batched conversion ----
  {
    CvPack p;
    const int CIDX[11] = {0, 3, 5, 11, 13, 19, 21, 27, 28, 29, 30};
    bf16* CDST[11] = {AP1 + 1024, wq1c, wk1c, wq2c, wk2c, wq3c, wk3c, cwg, cbg, cwfc, cbfc};
    int tot = 0;
    for (int t = 0; t < 11; ++t){
      p.src[t] = d_in[CIDX[t]];
      p.dst[t] = CDST[t];
      p.pre[t] = tot;
      int n = in_sizes[CIDX[t]];
      tot += n;
      if (t == 0){ p.rl[t] = 128; p.st[t] = 1152; }
      else       { p.rl[t] = n;   p.st[t] = n;    }
    }
    p.pre[11] = tot;
    convert_all<<<(tot + 255)/256, 256, 0, stream>>>(p, flagF);
  }

  // ---- indices + CSR (parallel scan) ----
  hipMemsetAsync(cnt, 0, (size_t)N_NODES*4, stream);
  conv_idx<<<(N_EDGES + 255)/256, 256, 0, stream>>>(ei, braw, flagI, src, dst, bat, cnt);
  scanA<<<40, 256, 0, stream>>>(cnt, fillp, bsum, N_NODES);
  scanB<<<1, 64, 0, stream>>>(bsum, 40);
  scanC<<<40, 256, 0, stream>>>(bsum, fillp, row_ptr, N_NODES);
  fill_csr<<<(N_EDGES + 255)/256, 256, 0, stream>>>(dst, fillp, eids);

  // ---- merged setup ----
  {
    MhPack mp;
    mp.wk[0]=wk1c; mp.wk[1]=wk2c; mp.wk[2]=wk3c;
    mp.wq[0]=wq1c; mp.wq[1]=wq2c; mp.wq[2]=wq3c;
    mp.wzt[0]=Wzt1; mp.wzt[1]=Wzt2; mp.wzt[2]=Wzt3;
    mp.fin[0]=128; mp.fin[1]=512; mp.fin[2]=256;
    mp.c[0]=512; mp.c[1]=256; mp.c[2]=128;
    gemm_mh_all<<<dim3(4,4,24), 256, 0, stream>>>(mp);

    WvPack wp;
    wp.wv[0]=d_in[7];  wp.wv[1]=d_in[15]; wp.wv[2]=d_in[23];
    wp.ws[0]=d_in[9];  wp.ws[1]=d_in[17]; wp.ws[2]=d_in[25];
    wp.bt[0]=Wvt1; wp.bt[1]=Wvt2; wp.bt[2]=Wvt3;
    wp.fin[0]=128; wp.fin[1]=512; wp.fin[2]=256;
    wp.c[0]=512; wp.c[1]=256; wp.c[2]=128;
    wp.bx[0]=36; wp.bx[1]=144; wp.bx[2]=72;
    wp.by[0]=16; wp.by[1]=8;   wp.by[2]=4;
    prep_wv_all<<<dim3(144,16,3), 256, 0, stream>>>(wp, flagF);

    SmPack sp;
    sp.wkc[0]=wk1c; sp.wkc[1]=wk2c; sp.wkc[2]=wk3c;
    sp.bq[0]=d_in[4];  sp.bq[1]=d_in[12]; sp.bq[2]=d_in[20];
    sp.bv[0]=d_in[8];  sp.bv[1]=d_in[16]; sp.bv[2]=d_in[24];
    sp.bs[0]=d_in[10]; sp.bs[1]=d_in[18]; sp.bs[2]=d_in[26];
    sp.fin[0]=128; sp.fin[1]=512; sp.fin[2]=256;
    sp.c[0]=512; sp.c[1]=256; sp.c[2]=128;
    sp.tz[0]=tz1; sp.tz[1]=tz2; sp.tz[2]=tz3;
    sp.bp[0]=bp1; sp.bp[1]=bp2; sp.bp[2]=bp3;
    sp.mb[0]=mb1; sp.mb[1]=mb2; sp.mb[2]=mb3;
    sp.rb[0]=256;  sp.rb[1]=1024; sp.rb[2]=512;   // 8*Fin/4
    sp.bpb[0]=2;   sp.bpb[1]=1;   sp.bpb[2]=1;    // ceil(C/256)
    prep_small_all<<<dim3(1025,1,3), 256, 0, stream>>>(sp, flagF);
  }

  const int MT = (N_NODES + 127)/128;   // 79
  const float sc1 = 1.0f/sqrtf(512.f), sc2 = 1.0f/sqrtf(256.f), sc3 = 1.0f/sqrtf(128.f);

  // ================= layer 1 (Fin=128, C=512) =================
  gemm_bias<<<dim3(8, MT), 256, 0, stream>>>(AP1 + 1024, ldP1, Wzt1, tz1, z1, 1024, N_NODES, 1024, 128);
  node_edge<128,2><<<N_NODES, 256, 0, stream>>>(z1, 1024, 0, AP1, ldP1, row_ptr, eids, src, sc1);
  hipMemsetAsync(facc, 0, (size_t)N_NODES*512*4, stream);
  gemm_splitk<256><<<dim3(2, MT, 6), 256, 0, stream>>>(AP1, ldP1, Wvt1, facc, N_NODES, 512, 1152, 192);
  finalize_out<<<(N_NODES*512)/256, 256, 0, stream>>>(facc, bp1, mb1, row_ptr, 9, 511, N_NODES*512, AP2 + 4096, ldP2);

  // ================= layer 2 (Fin=512, C=256) =================
  if (big){
    gemm_bias<<<dim3(32, MT), 256, 0, stream>>>(AP2 + 4096, ldP2, Wzt2, tz2, z2, 4096, N_NODES, 4096, 512);
    node_edge<512,2><<<N_NODES, 256, 0, stream>>>(z2, 4096, 0, AP2, ldP2, row_ptr, eids, src, sc2);
  } else {
    for (int g = 0; g < 2; ++g){
      gemm_bias<<<dim3(16, MT), 256, 0, stream>>>(AP2 + 4096, ldP2, Wzt2 + (size_t)g*4*512*512, tz2 + g*4*512, z2, 2048, N_NODES, 2048, 512);
      node_edge<512,1><<<N_NODES, 256, 0, stream>>>(z2, 2048, g*4, AP2, ldP2, row_ptr, eids, src, sc2);
    }
  }
  hipMemsetAsync(facc, 0, (size_t)N_NODES*256*4, stream);
  gemm_splitk<256><<<dim3(1, MT, 12), 256, 0, stream>>>(AP2, ldP2, Wvt2, facc, N_NODES, 256, 4608, 384);
  finalize_out<<<(N_NODES*256)/256, 256, 0, stream>>>(facc, bp2, mb2, row_ptr, 8, 255, N_NODES*256, AP3 + 2048, ldP3);

  // ================= layer 3 (Fin=256, C=128) =================
  gemm_bias<<<dim3(16, MT), 256, 0, stream>>>(AP3 + 2048, ldP3, Wzt3, tz3, z3, 2048, N_NODES, 2048, 256);
  node_edge<256,2><<<N_NODES, 256, 0, stream>>>(z3, 2048, 0, AP3, ldP3, row_ptr, eids, src, sc3);
  hipMemsetAsync(facc, 0, (size_t)N_NODES*128*4, stream);
  gemm_splitk<128><<<dim3(1, MT, 12), 256, 0, stream>>>(AP3, ldP3, Wvt3, facc, N_NODES, 128, 2304, 192);
  finalize_out<<<(N_NODES*128)/256, 256, 0, stream>>>(facc, bp3, mb3, row_ptr, 7, 127, N_NODES*128, h3, 128);

  // ---- global attention pooling + fc ----
  hipMemsetAsync(poolz, 0, (size_t)(64 + 64 + 64*128)*4, stream);
  gate_compute<<<(N_NODES + 3)/4, 256, 0, stream>>>(h3, cwg, cbg, bat, gate, gmax);
  gate_expsum<<<(N_NODES + 255)/256, 256, 0, stream>>>(gate, bat, gmax, gsum);
  pool_weighted<<<(N_NODES + 3)/4, 256, 0, stream>>>(gate, gsum, bat, h3, gacc);
  final_fc<<<N_GRAPHS, 64, 0, stream>>>(gacc, cwfc, cbfc, d_out, flagF);
}

// Round 14
// 771.319 us; speedup vs baseline: 1.1599x; 1.1599x over previous
//
#include <hip/hip_runtime.h>
#include <math.h>

typedef __bf16 bf16;
typedef __bf16 bf16x8 __attribute__((ext_vector_type(8)));
typedef __bf16 bf16x4 __attribute__((ext_vector_type(4)));
typedef __bf16 bf16x2 __attribute__((ext_vector_type(2)));
typedef float f32x4 __attribute__((ext_vector_type(4)));

#define N_NODES 10000
#define N_EDGES 80000
#define N_GRAPHS 64

template<int EPL> struct VecT;
template<> struct VecT<8>{ typedef bf16x8 type; };
template<> struct VecT<4>{ typedef bf16x4 type; };
template<> struct VecT<2>{ typedef bf16x2 type; };

__device__ inline unsigned f2ord(float f){
  unsigned u = __float_as_uint(f);
  return (u & 0x80000000u) ? ~u : (u | 0x80000000u);
}
__device__ inline float ord2f(unsigned u){
  return (u & 0x80000000u) ? __uint_as_float(u & 0x7fffffffu) : __uint_as_float(~u);
}

__device__ inline void gload_lds16(const bf16* g, bf16* l){
  __builtin_amdgcn_global_load_lds(
      (const __attribute__((address_space(1))) unsigned int*)g,
      (__attribute__((address_space(3))) unsigned int*)l, 16, 0, 0);
}

__global__ __launch_bounds__(256) void detect_f32_k(const unsigned short* __restrict__ raw, int n,
                                                    int* __restrict__ flagF){
  int i = blockIdx.x*256 + threadIdx.x;
  if (i < n){
    unsigned e = (raw[i] >> 7) & 0xFFu;
    if (e >= 0xC0u) atomicOr(flagF, 1);
  }
}

// ---- batched conversion with strided-dst support ----
struct CvPack {
  const void* src[11];
  bf16* dst[11];
  int pre[12];
  int rl[11];
  int st[11];
};
__global__ __launch_bounds__(256) void convert_all(CvPack p, const int* __restrict__ flagF){
  int gid = blockIdx.x*256 + threadIdx.x;
  if (gid >= p.pre[11]) return;
  int t = 0;
  while (gid >= p.pre[t+1]) ++t;
  int i = gid - p.pre[t];
  bool f = (*flagF != 0);
  float v = f ? ((const float*)p.src[t])[i] : (float)((const bf16*)p.src[t])[i];
  int row = i / p.rl[t], col = i - row*p.rl[t];
  p.dst[t][(size_t)row*p.st[t] + col] = (bf16)v;
}

__global__ __launch_bounds__(256) void detect_i64(const int* __restrict__ raw, int* __restrict__ flag){
  int i = blockIdx.x*256 + threadIdx.x;
  if (i < 4000 && raw[2*i+1] != 0) atomicOr(flag, 1);   // flag!=0 => int32
}

// conv_idx + degree count fused (cnt pre-zeroed via memset)
__global__ __launch_bounds__(256) void conv_idx(const int* __restrict__ ei_raw,
                                                const int* __restrict__ b_raw,
                                                const int* __restrict__ flag,
                                                int* __restrict__ src, int* __restrict__ dst,
                                                int* __restrict__ bat, int* __restrict__ cnt){
  int i = blockIdx.x*256 + threadIdx.x;
  bool i32 = (*flag != 0);
  if (i < N_EDGES){
    int s = i32 ? ei_raw[i]   : ei_raw[2*i];
    int d = i32 ? ei_raw[N_EDGES + i] : ei_raw[2*(N_EDGES + i)];
    s = min(max(s, 0), N_NODES-1);
    d = min(max(d, 0), N_NODES-1);
    src[i] = s; dst[i] = d;
    atomicAdd(&cnt[d], 1);
  }
  if (i < N_NODES){
    int b = i32 ? b_raw[i] : b_raw[2*i];
    bat[i] = min(max(b, 0), N_GRAPHS-1);
  }
}

// ---------------- parallel scan (3 small dispatches) ----------------
__global__ __launch_bounds__(256) void scanA(const int* __restrict__ cnt, int* __restrict__ fill,
                                             int* __restrict__ bsum, int N){
  __shared__ int s[256];
  int i = blockIdx.x*256 + threadIdx.x;
  int v = (i < N) ? cnt[i] : 0;
  s[threadIdx.x] = v;
  __syncthreads();
  for (int d = 1; d < 256; d <<= 1){
    int t = (threadIdx.x >= d) ? s[threadIdx.x - d] : 0;
    __syncthreads();
    s[threadIdx.x] += t;
    __syncthreads();
  }
  if (i < N) fill[i] = s[threadIdx.x] - v;          // block-exclusive
  if (threadIdx.x == 255) bsum[blockIdx.x] = s[255];
}
__global__ __launch_bounds__(64) void scanB(int* __restrict__ bsum, int nb){
  if (threadIdx.x == 0){
    int a = 0;
    for (int b = 0; b < nb; ++b){ int t = bsum[b]; bsum[b] = a; a += t; }
  }
}
__global__ __launch_bounds__(256) void scanC(const int* __restrict__ bsum, int* __restrict__ fill,
                                             int* __restrict__ row_ptr, int N){
  int i = blockIdx.x*256 + threadIdx.x;
  if (i < N){
    int st = fill[i] + bsum[i >> 8];
    fill[i] = st;
    row_ptr[i] = st;
  }
  if (i == 0) row_ptr[N] = N_EDGES;   // dst clamped -> every edge counted
}

__global__ __launch_bounds__(256) void fill_csr(const int* __restrict__ dst,
                                                int* __restrict__ fill, int* __restrict__ eids){
  int e = blockIdx.x*256 + threadIdx.x;
  if (e < N_EDGES){
    int p = atomicAdd(&fill[dst[e]], 1);
    eids[p] = e;
  }
}

// ---------------- GEMM: C[M][N] = A[M][K](lda) @ Bt[N][K] + bias ----------------
__global__ __launch_bounds__(256)
void gemm_bias(const bf16* __restrict__ A, int lda,
               const bf16* __restrict__ Bt,
               const bf16* __restrict__ bias, bf16* __restrict__ Cout, int ldc,
               int M, int N, int K)
{
  __shared__ bf16 As[128*64];
  __shared__ bf16 Bs[128*64];
  const int tid = threadIdx.x;
  const int lane = tid & 63;
  const int wave = tid >> 6;
  const int m0 = blockIdx.y * 128, n0 = blockIdx.x * 128;
  const int wm = (wave >> 1) * 64, wn = (wave & 1) * 64;
  const int l15 = lane & 15, l4 = lane >> 4;
  const int srow = lane >> 3;
  const int schunk = lane & 7;

  f32x4 acc[4][4] = {};

  for (int k0 = 0; k0 < K; k0 += 64){
    #pragma unroll
    for (int j = 0; j < 4; ++j){
      int r0 = (wave*4 + j)*8;
      int r  = r0 + srow;
      int gc = schunk ^ (r & 7);
      int ga = m0 + r; if (ga >= M) ga = M-1;
      gload_lds16(A  + (size_t)ga*lda      + k0 + gc*8, As + r0*64);
      gload_lds16(Bt + (size_t)(n0 + r)*K  + k0 + gc*8, Bs + r0*64);
    }
    __syncthreads();
    #pragma unroll
    for (int kt = 0; kt < 2; ++kt){
      bf16x8 af[4], bfr[4];
      #pragma unroll
      for (int mt = 0; mt < 4; ++mt){
        int row = wm + mt*16 + l15;
        int p = (kt*4 + l4) ^ (l15 & 7);
        af[mt] = *(const bf16x8*)(As + row*64 + p*8);
      }
      #pragma unroll
      for (int nt = 0; nt < 4; ++nt){
        int row = wn + nt*16 + l15;
        int p = (kt*4 + l4) ^ (l15 & 7);
        bfr[nt] = *(const bf16x8*)(Bs + row*64 + p*8);
      }
      #pragma unroll
      for (int mt = 0; mt < 4; ++mt)
        #pragma unroll
        for (int nt = 0; nt < 4; ++nt)
          acc[mt][nt] = __builtin_amdgcn_mfma_f32_16x16x32_bf16(af[mt], bfr[nt], acc[mt][nt], 0, 0, 0);
    }
    __syncthreads();
  }

  #pragma unroll
  for (int nt = 0; nt < 4; ++nt){
    int col = n0 + wn + nt*16 + l15;
    float bv = (float)bias[col];
    #pragma unroll
    for (int mt = 0; mt < 4; ++mt){
      int rbase = m0 + wm + mt*16 + l4*4;
      #pragma unroll
      for (int r = 0; r < 4; ++r){
        int row = rbase + r;
        if (row < M) Cout[(size_t)row*ldc + col] = (bf16)(acc[mt][nt][r] + bv);
      }
    }
  }
}

// ---------------- split-K GEMM, 128x128 tile: atomic f32 accumulate (r10-proven config) ----
__global__ __launch_bounds__(256)
void gemm_splitk(const bf16* __restrict__ A, int lda,
                 const bf16* __restrict__ Bt, float* __restrict__ Cacc,
                 int M, int N, int K, int ks)
{
  __shared__ bf16 As[128*64];
  __shared__ bf16 Bs[128*64];
  const int tid = threadIdx.x;
  const int lane = tid & 63;
  const int wave = tid >> 6;
  const int m0 = blockIdx.y * 128, n0 = blockIdx.x * 128;
  const int wm = (wave >> 1) * 64, wn = (wave & 1) * 64;
  const int l15 = lane & 15, l4 = lane >> 4;
  const int srow = lane >> 3;
  const int schunk = lane & 7;
  const int kb = blockIdx.z * ks;
  const int ke = min(K, kb + ks);

  f32x4 acc[4][4] = {};

  for (int k0 = kb; k0 < ke; k0 += 64){
    #pragma unroll
    for (int j = 0; j < 4; ++j){
      int r0 = (wave*4 + j)*8;
      int r  = r0 + srow;
      int gc = schunk ^ (r & 7);
      int ga = m0 + r; if (ga >= M) ga = M-1;
      gload_lds16(A  + (size_t)ga*lda     + k0 + gc*8, As + r0*64);
      gload_lds16(Bt + (size_t)(n0 + r)*K + k0 + gc*8, Bs + r0*64);
    }
    __syncthreads();
    #pragma unroll
    for (int kt = 0; kt < 2; ++kt){
      bf16x8 af[4], bfr[4];
      #pragma unroll
      for (int mt = 0; mt < 4; ++mt){
        int row = wm + mt*16 + l15;
        int p = (kt*4 + l4) ^ (l15 & 7);
        af[mt] = *(const bf16x8*)(As + row*64 + p*8);
      }
      #pragma unroll
      for (int nt = 0; nt < 4; ++nt){
        int row = wn + nt*16 + l15;
        int p = (kt*4 + l4) ^ (l15 & 7);
        bfr[nt] = *(const bf16x8*)(Bs + row*64 + p*8);
      }
      #pragma unroll
      for (int mt = 0; mt < 4; ++mt)
        #pragma unroll
        for (int nt = 0; nt < 4; ++nt)
          acc[mt][nt] = __builtin_amdgcn_mfma_f32_16x16x32_bf16(af[mt], bfr[nt], acc[mt][nt], 0, 0, 0);
    }
    __syncthreads();
  }

  #pragma unroll
  for (int nt = 0; nt < 4; ++nt){
    int col = n0 + wn + nt*16 + l15;
    #pragma unroll
    for (int mt = 0; mt < 4; ++mt){
      int rbase = m0 + wm + mt*16 + l4*4;
      #pragma unroll
      for (int r = 0; r < 4; ++r){
        int row = rbase + r;
        if (row < M) atomicAdd(&Cacc[(size_t)row*N + col], acc[mt][nt][r]);
      }
    }
  }
}

// ---------------- finalize: bias + deg0 fixup + ELU + strided store; zeroes facc for next layer ----
__global__ __launch_bounds__(256)
void finalize_out(float* __restrict__ facc, const bf16* __restrict__ bp,
                  const bf16* __restrict__ mb, const int* __restrict__ row_ptr,
                  int shift, int mask, int total, bf16* __restrict__ out, int ldo)
{
  int idx = blockIdx.x*256 + threadIdx.x;
  if (idx >= total) return;
  int n = idx >> shift, c = idx & mask;
  bool d0 = (row_ptr[n+1] == row_ptr[n]);
  float v = facc[idx] + (float)bp[c] - (d0 ? (float)mb[c] : 0.f);
  facc[idx] = 0.f;                       // pre-zero for next layer's split-K
  v = (v > 0.f) ? v : (__expf(v) - 1.f);
  out[(size_t)n*ldo + c] = (bf16)v;
}

// ---------------- L3 finalize fused with gate computation ----------------
// block = 256 threads = 2 rows of 128; writes h3, gate[n], atomicMax gmax[batch].
__global__ __launch_bounds__(256)
void finalize_gate(const float* __restrict__ facc, const bf16* __restrict__ bp,
                   const bf16* __restrict__ mb, const int* __restrict__ row_ptr,
                   bf16* __restrict__ hout, const bf16* __restrict__ wg,
                   const bf16* __restrict__ bg, const int* __restrict__ bat,
                   float* __restrict__ gate, unsigned* __restrict__ gmax)
{
  __shared__ float wred[4];
  int idx = blockIdx.x*256 + threadIdx.x;     // < N_NODES*128
  int n = idx >> 7, c = idx & 127;
  bool d0 = (row_ptr[n+1] == row_ptr[n]);
  float v = facc[idx] + (float)bp[c] - (d0 ? (float)mb[c] : 0.f);
  v = (v > 0.f) ? v : (__expf(v) - 1.f);
  hout[idx] = (bf16)v;
  float gc = v * (float)wg[c];
  #pragma unroll
  for (int o = 32; o; o >>= 1) gc += __shfl_xor(gc, o, 64);
  int wave = threadIdx.x >> 6;
  if ((threadIdx.x & 63) == 0) wred[wave] = gc;
  __syncthreads();
  if ((threadIdx.x & 127) == 0){
    float g = wred[wave] + wred[wave + 1] + (float)bg[0];
    gate[n] = g;
    atomicMax(&gmax[bat[n]], f2ord(g));
  }
}

// ---------------- merged M_h precompute (all 3 layers, 1 dispatch) ----------------
struct MhPack { const bf16* wk[3]; const bf16* wq[3]; bf16* wzt[3]; int fin[3]; int c[3]; };
__global__ __launch_bounds__(256)
void gemm_mh_all(MhPack P)
{
  const int L = blockIdx.z >> 3, h = blockIdx.z & 7;
  const int Fin = P.fin[L], C = P.c[L];
  const int nb = Fin >> 7;
  if ((int)blockIdx.x >= nb || (int)blockIdx.y >= nb) return;
  __shared__ bf16 As[128*64];
  __shared__ bf16 Bs[128*64];
  const int ld = 8*C;
  const bf16* Ab = P.wk[L] + h*C;
  const bf16* Bb = P.wq[L] + h*C;
  bf16* Cb = P.wzt[L] + (size_t)h*Fin*Fin;
  const int tid = threadIdx.x;
  const int lane = tid & 63;
  const int wave = tid >> 6;
  const int m0 = blockIdx.y * 128, n0 = blockIdx.x * 128;
  const int wm = (wave >> 1) * 64, wn = (wave & 1) * 64;
  const int l15 = lane & 15, l4 = lane >> 4;
  const int srow = lane >> 3;
  const int schunk = lane & 7;

  f32x4 acc[4][4] = {};

  for (int k0 = 0; k0 < C; k0 += 64){
    #pragma unroll
    for (int j = 0; j < 4; ++j){
      int r0 = (wave*4 + j)*8;
      int r  = r0 + srow;
      int gc = schunk ^ (r & 7);
      gload_lds16(Ab + (size_t)(m0 + r)*ld + k0 + gc*8, As + r0*64);
      gload_lds16(Bb + (size_t)(n0 + r)*ld + k0 + gc*8, Bs + r0*64);
    }
    __syncthreads();
    #pragma unroll
    for (int kt = 0; kt < 2; ++kt){
      bf16x8 af[4], bfr[4];
      #pragma unroll
      for (int mt = 0; mt < 4; ++mt){
        int row = wm + mt*16 + l15;
        int p = (kt*4 + l4) ^ (l15 & 7);
        af[mt] = *(const bf16x8*)(As + row*64 + p*8);
      }
      #pragma unroll
      for (int nt = 0; nt < 4; ++nt){
        int row = wn + nt*16 + l15;
        int p = (kt*4 + l4) ^ (l15 & 7);
        bfr[nt] = *(const bf16x8*)(Bs + row*64 + p*8);
      }
      #pragma unroll
      for (int mt = 0; mt < 4; ++mt)
        #pragma unroll
        for (int nt = 0; nt < 4; ++nt)
          acc[mt][nt] = __builtin_amdgcn_mfma_f32_16x16x32_bf16(af[mt], bfr[nt], acc[mt][nt], 0, 0, 0);
    }
    __syncthreads();
  }

  #pragma unroll
  for (int nt = 0; nt < 4; ++nt){
    int col = n0 + wn + nt*16 + l15;
    #pragma unroll
    for (int mt = 0; mt < 4; ++mt){
      int rbase = m0 + wm + mt*16 + l4*4;
      #pragma unroll
      for (int r = 0; r < 4; ++r)
        Cb[(size_t)(rbase + r)*Fin + col] = (bf16)acc[mt][nt][r];
    }
  }
}

// ---------------- merged Wv/Ws prep (all 3 layers) ----------------
struct WvPack { const void* wv[3]; const void* ws[3]; bf16* bt[3]; int fin[3]; int c[3]; int bx[3]; int by[3]; };
__global__ __launch_bounds__(256)
void prep_wv_all(WvPack P, const int* __restrict__ flagF)
{
  const int L = blockIdx.z;
  if ((int)blockIdx.x >= P.bx[L] || (int)blockIdx.y >= P.by[L]) return;
  __shared__ float t[32][33];
  bool f = (*flagF != 0);
  const int Fin = P.fin[L], C = P.c[L];
  int k0 = blockIdx.x*32, j0 = blockIdx.y*32;
  int x = threadIdx.x & 31, y = threadIdx.x >> 5;
  const void* srcp; int nstride, cb; float sc; int i0;
  if (k0 < 8*Fin){
    int h = k0 / Fin; i0 = k0 - h*Fin;
    srcp = P.wv[L]; nstride = 8*C; cb = h*C + j0; sc = 0.125f;
  } else {
    i0 = k0 - 8*Fin;
    srcp = P.ws[L]; nstride = C; cb = j0; sc = 1.0f;
  }
  #pragma unroll
  for (int ii = 0; ii < 4; ++ii){
    int i = i0 + y + ii*8;
    size_t idx = (size_t)i*nstride + cb + x;
    float v = f ? ((const float*)srcp)[idx] : (float)((const bf16*)srcp)[idx];
    t[y + ii*8][x] = v*sc;
  }
  __syncthreads();
  #pragma unroll
  for (int ii = 0; ii < 4; ++ii){
    int j = j0 + y + ii*8;
    P.bt[L][(size_t)j*(9*Fin) + k0 + x] = (bf16)t[x][y + ii*8];
  }
}

// ---------------- merged small prep (all 3 layers), wave-per-row ----------------
struct SmPack { const bf16* wkc[3]; const void* bq[3]; const void* bv[3]; const void* bs[3];
                int fin[3]; int c[3]; bf16* tz[3]; bf16* bp[3]; bf16* mb[3]; int rb[3]; int bpb[3]; };
__global__ __launch_bounds__(256)
void prep_small_all(SmPack P, const int* __restrict__ flagF)
{
  const int L = blockIdx.z;
  const int Fin = P.fin[L], C = P.c[L];
  const int rb = P.rb[L];
  if ((int)blockIdx.x >= rb + P.bpb[L]) return;
  bool f = (*flagF != 0);
  if ((int)blockIdx.x < rb){
    int wave = threadIdx.x >> 6, lane = threadIdx.x & 63;
    int r = blockIdx.x*4 + wave;            // r < 8*Fin (rb = 8*Fin/4)
    int h = r / Fin, i = r - h*Fin;
    int epc = C >> 6;
    const bf16* wp = P.wkc[L] + (size_t)i*8*C + h*C;
    const void* bqp = P.bq[L];
    float s = 0.f;
    for (int k = 0; k < epc; ++k){
      int c = k*64 + lane;
      float b = f ? ((const float*)bqp)[h*C + c] : (float)((const bf16*)bqp)[h*C + c];
      s += (float)wp[c] * b;
    }
    #pragma unroll
    for (int o = 32; o; o >>= 1) s += __shfl_xor(s, o, 64);
    if (lane == 0) P.tz[L][r] = (bf16)s;
  } else {
    int idx = ((int)blockIdx.x - rb)*256 + threadIdx.x;
    if (idx < C){
      float s = 0.f;
      for (int h = 0; h < 8; ++h)
        s += f ? ((const float*)P.bv[L])[h*C + idx] : (float)((const bf16*)P.bv[L])[h*C + idx];
      s *= 0.125f;
      float bsv = f ? ((const float*)P.bs[L])[idx] : (float)((const bf16*)P.bs[L])[idx];
      P.mb[L][idx] = (bf16)s;
      P.bp[L][idx] = (bf16)(s + bsv);
    }
  }
}

// ---------------- edge phase: scores via z.h_s (bias pre-folded), softmax, P = sum alpha h_s ----
template<int Fin, int NH>
__global__ __launch_bounds__(256)
void node_edge(const bf16* __restrict__ z, int zw, int hbase,
               bf16* __restrict__ AP, int ldP,
               const int* __restrict__ row_ptr, const int* __restrict__ eids,
               const int* __restrict__ srcv, float scale)
{
  constexpr int EPL = Fin/64;
  constexpr int NQ  = Fin/128;
  typedef typename VecT<EPL>::type vecb;
  __shared__ int   sSrc[256];
  __shared__ float sw[4][NH][256];

  int n = blockIdx.x;
  int beg = row_ptr[n], deg = row_ptr[n+1] - beg;
  if (deg > 256) deg = 256;   // deg ~ Poisson(8); P(deg>256) ~ 0
  int wave = threadIdx.x >> 6, lane = threadIdx.x & 63;
  int sub = lane >> 4, sl = lane & 15;

  for (int i = threadIdx.x; i < deg; i += 256) sSrc[i] = srcv[eids[beg + i]];
  __syncthreads();

  float zr[NH][NQ*8];
  #pragma unroll
  for (int j = 0; j < NH; ++j){
    const bf16* zp = z + (size_t)n*zw + (wave + j*4)*Fin;
    #pragma unroll
    for (int c = 0; c < NQ; ++c){
      bf16x8 v = *(const bf16x8*)(zp + c*128 + sl*8);
      #pragma unroll
      for (int k = 0; k < 8; ++k) zr[j][c*8+k] = (float)v[k];
    }
  }

  float acc[NH][EPL];
  #pragma unroll
  for (int j = 0; j < NH; ++j)
    #pragma unroll
    for (int k = 0; k < EPL; ++k) acc[j][k] = 0.f;

  if (deg > 0){
    for (int i0 = 0; i0 < deg; i0 += 4){
      int e = i0 + sub;
      int sn = (e < deg) ? sSrc[e] : 0;
      float s[NH];
      #pragma unroll
      for (int j = 0; j < NH; ++j) s[j] = 0.f;
      const bf16* hp = AP + (size_t)sn*ldP + 8*Fin;
      #pragma unroll
      for (int c = 0; c < NQ; ++c){
        bf16x8 hv = *(const bf16x8*)(hp + c*128 + sl*8);
        #pragma unroll
        for (int k = 0; k < 8; ++k){
          float xv = (float)hv[k];
          #pragma unroll
          for (int j = 0; j < NH; ++j) s[j] += zr[j][c*8+k]*xv;
        }
      }
      #pragma unroll
      for (int j = 0; j < NH; ++j){
        #pragma unroll
        for (int o = 1; o < 16; o <<= 1) s[j] += __shfl_xor(s[j], o, 64);
      }
      if (sl == 0 && e < deg){
        #pragma unroll
        for (int j = 0; j < NH; ++j)
          sw[wave][j][e] = s[j] * scale;
      }
    }
    #pragma unroll
    for (int j = 0; j < NH; ++j){
      float m = -3.4e38f;
      for (int i = lane; i < deg; i += 64) m = fmaxf(m, sw[wave][j][i]);
      #pragma unroll
      for (int o = 32; o; o >>= 1) m = fmaxf(m, __shfl_xor(m, o, 64));
      float ss = 0.f;
      for (int i = lane; i < deg; i += 64) ss += __expf(sw[wave][j][i] - m);
      #pragma unroll
      for (int o = 32; o; o >>= 1) ss += __shfl_xor(ss, o, 64);
      float inv = 1.f/(ss + 1e-16f);
      for (int i = lane; i < deg; i += 64) sw[wave][j][i] = __expf(sw[wave][j][i] - m)*inv;
    }
    for (int i = 0; i < deg; ++i){
      vecb hv = *(const vecb*)(AP + (size_t)sSrc[i]*ldP + 8*Fin + lane*EPL);
      #pragma unroll
      for (int j = 0; j < NH; ++j){
        float w = sw[wave][j][i];
        #pragma unroll
        for (int k = 0; k < EPL; ++k) acc[j][k] += w*(float)hv[k];
      }
    }
  }

  #pragma unroll
  for (int j = 0; j < NH; ++j){
    vecb outv;
    #pragma unroll
    for (int k = 0; k < EPL; ++k) outv[k] = (bf16)acc[j][k];
    *(vecb*)(AP + (size_t)n*ldP + (hbase + wave + j*4)*Fin + lane*EPL) = outv;
  }
}

// ---------------- pooling ----------------
__global__ __launch_bounds__(256) void gate_expsum(float* __restrict__ gate, const int* __restrict__ bat,
                                                   const unsigned* __restrict__ gmax, float* __restrict__ gsum){
  int n = blockIdx.x*256 + threadIdx.x;
  if (n < N_NODES){
    float e = __expf(gate[n] - ord2f(gmax[bat[n]]));
    gate[n] = e;
    atomicAdd(&gsum[bat[n]], e);
  }
}

__global__ __launch_bounds__(256) void pool_weighted(const float* __restrict__ gate, const float* __restrict__ gsum,
                                                     const int* __restrict__ bat, const bf16* __restrict__ h,
                                                     float* __restrict__ gacc){
  int n = blockIdx.x*4 + (threadIdx.x >> 6);
  if (n >= N_NODES) return;
  int lane = threadIdx.x & 63;
  int b = bat[n];
  float w = gate[n]/(gsum[b] + 1e-16f);
  atomicAdd(&gacc[b*128 + lane],      w*(float)h[(size_t)n*128 + lane]);
  atomicAdd(&gacc[b*128 + 64 + lane], w*(float)h[(size_t)n*128 + 64 + lane]);
}

__global__ __launch_bounds__(64) void final_fc(const float* __restrict__ gacc, const bf16* __restrict__ wfc,
                                               const bf16* __restrict__ bfc, void* __restrict__ out,
                                               const int* __restrict__ flagF){
  int g = blockIdx.x;
  int o = threadIdx.x;
  if (o < 10){
    float s = (float)bfc[o];
    for (int c = 0; c < 128; ++c) s += gacc[g*128 + c]*(float)wfc[c*10 + o];
    if (*flagF) ((float*)out)[(size_t)g*10 + o] = s;
    else        ((bf16*)out)[(size_t)g*10 + o]  = (bf16)s;
  }
}

extern "C" void kernel_launch(void* const* d_in, const int* in_sizes, int n_in,
                              void* d_out, int out_size, void* d_ws, size_t ws_size,
                              hipStream_t stream)
{
  const int* ei   = (const int*)d_in[1];
  const int* braw = (const int*)d_in[2];

  // ---- workspace plan (arena-aliased); adaptive A2 size for one-shot layer-2 ----
  bf16 *Wzt1=0,*Wzt2=0,*Wzt3=0,*Wvt1=0,*Wvt2=0,*Wvt3=0;
  float *facc=0,*gate=0;
  bf16 *tz1=0,*tz2=0,*tz3=0,*bp1=0,*mb1=0,*bp2=0,*mb2=0,*bp3=0,*mb3=0,*h3=0;
  bf16 *cwg=0,*cbg=0,*cwfc=0,*cbfc=0;
  int *src=0,*dst=0,*bat=0,*cnt=0,*row_ptr=0,*fillp=0,*eids=0,*flagbuf=0;
  char *A1=0, *A2=0;

  auto plan = [&](bool big)->size_t{
    size_t off = 0;
    auto A = [&](size_t bytes)->char*{
      char* p = (char*)d_ws + off;
      off += (bytes + 255) & ~(size_t)255;
      return p;
    };
    A1 = A(92160000);
    A2 = A(big ? 81920000 : 46080000);
    Wzt1 = (bf16*)A((size_t)8*128*128*2);
    Wzt2 = (bf16*)A((size_t)8*512*512*2);
    Wzt3 = (bf16*)A((size_t)8*256*256*2);
    Wvt1 = (bf16*)A((size_t)512*9*128*2);
    Wvt2 = (bf16*)A((size_t)256*9*512*2);
    Wvt3 = (bf16*)A((size_t)128*9*256*2);
    facc = (float*)A((size_t)N_NODES*512*4);
    tz1  = (bf16*)A(8*128*2);
    tz2  = (bf16*)A(8*512*2);
    tz3  = (bf16*)A(8*256*2);
    bp1  = (bf16*)A(512*2);  mb1 = (bf16*)A(512*2);
    bp2  = (bf16*)A(256*2);  mb2 = (bf16*)A(256*2);
    bp3  = (bf16*)A(128*2);  mb3 = (bf16*)A(128*2);
    h3   = (bf16*)A((size_t)N_NODES*128*2);
    src  = (int*)A((size_t)N_EDGES*4);
    dst  = (int*)A((size_t)N_EDGES*4);
    bat  = (int*)A((size_t)N_NODES*4);
    cnt  = (int*)A((size_t)N_NODES*4);
    row_ptr = (int*)A((size_t)(N_NODES+1)*4);
    fillp= (int*)A((size_t)N_NODES*4);
    eids = (int*)A((size_t)N_EDGES*4);
    flagbuf = (int*)A(16384);
    gate = (float*)A((size_t)N_NODES*4);
    unsigned* poolz = (unsigned*)A((size_t)(64 + 64 + 64*128)*4);
    (void)poolz;
    cwg  = (bf16*)A(128*2);
    cbg  = (bf16*)A(2*2);
    cwfc = (bf16*)A(1280*2);
    cbfc = (bf16*)A(10*2);
    return off;
  };

  bool big = (plan(true) <= ws_size);
  if (!big && plan(false) > ws_size) return;   // floor plan doesn't fit; visible failure
  plan(big);
  unsigned* poolz = (unsigned*)((char*)gate + (((size_t)N_NODES*4 + 255) & ~(size_t)255));

  int* flagI = flagbuf;
  int* flagF = flagbuf + 1;
  int* bsum  = (int*)((char*)flagbuf + 8192);
  unsigned* gmax = poolz;
  float*    gsum = (float*)(poolz + 64);
  float*    gacc = (float*)(poolz + 128);

  bf16* AP1 = (bf16*)A2;   const int ldP1 = 1152;   // [P(1024)|x(128)]
  bf16* z1  = (bf16*)A1;
  bf16* AP2 = (bf16*)A1;   const int ldP2 = 4608;   // [P(4096)|h1(512)]
  bf16* z2  = (bf16*)A2;                            // group (2048w) or big (4096w)
  bf16* AP3 = (bf16*)A2;   const int ldP3 = 2304;   // [P(2048)|h2(256)]
  bf16* z3  = (bf16*)A1;
  bf16* wq1c = (bf16*)(A1 + 48000000);  bf16* wk1c = wq1c + 128*4096;
  bf16* wq2c = wk1c + 128*4096;         bf16* wk2c = wq2c + 512*2048;
  bf16* wq3c = wk2c + 512*2048;         bf16* wk3c = wq3c + 256*1024;

  // ---- detection ----
  hipMemsetAsync(flagbuf, 0, 16384, stream);
  {
    int nprobe = in_sizes[0] < 32768 ? in_sizes[0] : 32768;
    detect_f32_k<<<(nprobe + 255)/256, 256, 0, stream>>>((const unsigned short*)d_in[0], nprobe, flagF);
    detect_i64<<<16, 256, 0, stream>>>(ei, flagI);
  }

  // ---- batched conversion ----
  {
    CvPack p;
    const int CIDX[11] = {0, 3, 5, 11, 13, 19, 21, 27, 28, 29, 30};
    bf16* CDST[11] = {AP1 + 1024, wq1c, wk1c, wq2c, wk2c, wq3c, wk3c, cwg, cbg, cwfc, cbfc};
    int tot = 0;
    for (int t = 0; t < 11; ++t){
      p.src[t] = d_in[CIDX[t]];
      p.dst[t] = CDST[t];
      p.pre[t] = tot;
      int n = in_sizes[CIDX[t]];
      tot += n;
      if (t == 0){ p.rl[t] = 128; p.st[t] = 1152; }
      else       { p.rl[t] = n;   p.st[t] = n;    }
    }
    p.pre[11] = tot;
    convert_all<<<(tot + 255)/256, 256, 0, stream>>>(p, flagF);
  }

  // ---- indices + CSR (parallel scan) ----
  hipMemsetAsync(cnt, 0, (size_t)N_NODES*4, stream);
  conv_idx<<<(N_EDGES + 255)/256, 256, 0, stream>>>(ei, braw, flagI, src, dst, bat, cnt);
  scanA<<<40, 256, 0, stream>>>(cnt, fillp, bsum, N_NODES);
  scanB<<<1, 64, 0, stream>>>(bsum, 40);
  scanC<<<40, 256, 0, stream>>>(bsum, fillp, row_ptr, N_NODES);
  fill_csr<<<(N_EDGES + 255)/256, 256, 0, stream>>>(dst, fillp, eids);

  // ---- merged setup ----
  {
    MhPack mp;
    mp.wk[0]=wk1c; mp.wk[1]=wk2c; mp.wk[2]=wk3c;
    mp.wq[0]=wq1c; mp.wq[1]=wq2c; mp.wq[2]=wq3c;
    mp.wzt[0]=Wzt1; mp.wzt[1]=Wzt2; mp.wzt[2]=Wzt3;
    mp.fin[0]=128; mp.fin[1]=512; mp.fin[2]=256;
    mp.c[0]=512; mp.c[1]=256; mp.c[2]=128;
    gemm_mh_all<<<dim3(4,4,24), 256, 0, stream>>>(mp);

    WvPack wp;
    wp.wv[0]=d_in[7];  wp.wv[1]=d_in[15]; wp.wv[2]=d_in[23];
    wp.ws[0]=d_in[9];  wp.ws[1]=d_in[17]; wp.ws[2]=d_in[25];
    wp.bt[0]=Wvt1; wp.bt[1]=Wvt2; wp.bt[2]=Wvt3;
    wp.fin[0]=128; wp.fin[1]=512; wp.fin[2]=256;
    wp.c[0]=512; wp.c[1]=256; wp.c[2]=128;
    wp.bx[0]=36; wp.bx[1]=144; wp.bx[2]=72;
    wp.by[0]=16; wp.by[1]=8;   wp.by[2]=4;
    prep_wv_all<<<dim3(144,16,3), 256, 0, stream>>>(wp, flagF);

    SmPack sp;
    sp.wkc[0]=wk1c; sp.wkc[1]=wk2c; sp.wkc[2]=wk3c;
    sp.bq[0]=d_in[4];  sp.bq[1]=d_in[12]; sp.bq[2]=d_in[20];
    sp.bv[0]=d_in[8];  sp.bv[1]=d_in[16]; sp.bv[2]=d_in[24];
    sp.bs[0]=d_in[10]; sp.bs[1]=d_in[18]; sp.bs[2]=d_in[26];
    sp.fin[0]=128; sp.fin[1]=512; sp.fin[2]=256;
    sp.c[0]=512; sp.c[1]=256; sp.c[2]=128;
    sp.tz[0]=tz1; sp.tz[1]=tz2; sp.tz[2]=tz3;
    sp.bp[0]=bp1; sp.bp[1]=bp2; sp.bp[2]=bp3;
    sp.mb[0]=mb1; sp.mb[1]=mb2; sp.mb[2]=mb3;
    sp.rb[0]=256;  sp.rb[1]=1024; sp.rb[2]=512;   // 8*Fin/4
    sp.bpb[0]=2;   sp.bpb[1]=1;   sp.bpb[2]=1;    // ceil(C/256)
    prep_small_all<<<dim3(1025,1,3), 256, 0, stream>>>(sp, flagF);
  }

  const int MT = (N_NODES + 127)/128;   // 79
  const float sc1 = 1.0f/sqrtf(512.f), sc2 = 1.0f/sqrtf(256.f), sc3 = 1.0f/sqrtf(128.f);

  // facc zeroed once; finalize_out re-zeroes what it reads for the next layer
  hipMemsetAsync(facc, 0, (size_t)N_NODES*512*4, stream);
  hipMemsetAsync(poolz, 0, (size_t)(64 + 64 + 64*128)*4, stream);

  // ================= layer 1 (Fin=128, C=512) =================
  gemm_bias<<<dim3(8, MT), 256, 0, stream>>>(AP1 + 1024, ldP1, Wzt1, tz1, z1, 1024, N_NODES, 1024, 128);
  node_edge<128,2><<<N_NODES, 256, 0, stream>>>(z1, 1024, 0, AP1, ldP1, row_ptr, eids, src, sc1);
  gemm_splitk<<<dim3(4, MT, 3), 256, 0, stream>>>(AP1, ldP1, Wvt1, facc, N_NODES, 512, 1152, 384);
  finalize_out<<<(N_NODES*512)/256, 256, 0, stream>>>(facc, bp1, mb1, row_ptr, 9, 511, N_NODES*512, AP2 + 4096, ldP2);

  // ================= layer 2 (Fin=512, C=256) =================
  if (big){
    gemm_bias<<<dim3(32, MT), 256, 0, stream>>>(AP2 + 4096, ldP2, Wzt2, tz2, z2, 4096, N_NODES, 4096, 512);
    node_edge<512,2><<<N_NODES, 256, 0, stream>>>(z2, 4096, 0, AP2, ldP2, row_ptr, eids, src, sc2);
  } else {
    for (int g = 0; g < 2; ++g){
      gemm_bias<<<dim3(16, MT), 256, 0, stream>>>(AP2 + 4096, ldP2, Wzt2 + (size_t)g*4*512*512, tz2 + g*4*512, z2, 2048, N_NODES, 2048, 512);
      node_edge<512,1><<<N_NODES, 256, 0, stream>>>(z2, 2048, g*4, AP2, ldP2, row_ptr, eids, src, sc2);
    }
  }
  gemm_splitk<<<dim3(2, MT, 6), 256, 0, stream>>>(AP2, ldP2, Wvt2, facc, N_NODES, 256, 4608, 768);
  finalize_out<<<(N_NODES*256)/256, 256, 0, stream>>>(facc, bp2, mb2, row_ptr, 8, 255, N_NODES*256, AP3 + 2048, ldP3);

  // ================= layer 3 (Fin=256, C=128) =================
  gemm_bias<<<dim3(16, MT), 256, 0, stream>>>(AP3 + 2048, ldP3, Wzt3, tz3, z3, 2048, N_NODES, 2048, 256);
  node_edge<256,2><<<N_NODES, 256, 0, stream>>>(z3, 2048, 0, AP3, ldP3, row_ptr, eids, src, sc3);
  gemm_splitk<<<dim3(1, MT, 6), 256, 0, stream>>>(AP3, ldP3, Wvt3, facc, N_NODES, 128, 2304, 384);
  finalize_gate<<<(N_NODES*128)/256, 256, 0, stream>>>(facc, bp3, mb3, row_ptr, h3, cwg, cbg, bat, gate, gmax);

  // ---- global attention pooling + fc ----
  gate_expsum<<<(N_NODES + 255)/256, 256, 0, stream>>>(gate, bat, gmax, gsum);
  pool_weighted<<<(N_NODES + 3)/4, 256, 0, stream>>>(gate, gsum, bat, h3, gacc);
  final_fc<<<N_GRAPHS, 64, 0, stream>>>(gacc, cwfc, cbfc, d_out, flagF);
}